// Round 3
// baseline (121.512 us; speedup 1.0000x reference)
//
#include <hip/hip_runtime.h>

// LIF "RepeatEncoder": input (B,L,C) f32, output spikes (T,B,C,L) f32.
// v=0; per t: v = v + (a - v)*0.5; s = (v >= 1); v = s ? 0 : v; out[t,b,c,l] = s.
// Input is time-constant, so each thread runs the 16-step recurrence privately.
//
// Round-3 change: 32l x 64c block tile -> 2048 blocks = 8 blocks/CU = exactly
// 32 waves/CU (single wave-round, no tail). Each thread owns 8 l values ->
// 32 independent float4 nt-stores for deeper write pipelining.

#define T_STEPS 16
#define B 64
#define L 512
#define C 128
#define LT 32   // l-tile
#define CT 64   // c-tile

typedef float v4f __attribute__((ext_vector_type(4)));

__global__ __launch_bounds__(256, 8) void lif_repeat_kernel(const float* __restrict__ in,
                                                            float* __restrict__ out) {
    __shared__ float lds[LT][CT + 1];   // +1 pad: transposed reads max 2-way (free)

    const int blk = blockIdx.x;                 // 2048 blocks
    const int c0 = (blk & 1) * CT;              // 2 c-tiles
    const int l0 = ((blk >> 1) & 15) * LT;      // 16 l-tiles
    const int b  = blk >> 5;                    // 64 b
    const int tid = threadIdx.x;

    // Cooperative coalesced load of the 32x64 tile: in[b, l0+r, c0+cc].
    // Each wave covers one full row (64 floats = 256B contiguous).
    const float* inb = in + ((size_t)(b * L + l0)) * C + c0;
#pragma unroll
    for (int k = 0; k < 8; ++k) {
        const int e  = tid + 256 * k;   // 0..2047
        const int r  = e >> 6;          // l-row 0..31
        const int cc = e & 63;          // c    0..63
        lds[r][cc] = inb[(size_t)r * C + cc];
    }
    __syncthreads();

    // Compute mapping: lane sweeps l-group fastest so stores coalesce along l.
    const int lgrp = tid & 3;       // 4 groups of 8 l
    const int c    = tid >> 2;      // 0..63
    const int l    = lgrp * 8;

    float a[8], v[8];
#pragma unroll
    for (int k = 0; k < 8; ++k) {
        a[k] = lds[l + k][c];
        v[k] = 0.f;
    }

    float* outp = out + ((size_t)(b * C + c0 + c)) * L + l0 + l;
    const size_t plane = (size_t)B * C * L;

#pragma unroll
    for (int t = 0; t < T_STEPS; ++t) {
        float s[8];
#pragma unroll
        for (int k = 0; k < 8; ++k) {
            // Exact replication of reference arithmetic: v = v + (x - v)/2.
            // (x-v)*0.5 is exact, so FMA contraction cannot change bits.
            v[k] = v[k] + (a[k] - v[k]) * 0.5f;
            s[k] = (v[k] >= 1.0f) ? 1.0f : 0.0f;
            v[k] = (s[k] != 0.0f) ? 0.0f : v[k];
        }
        float* p = outp + (size_t)t * plane;
        __builtin_nontemporal_store((v4f){s[0], s[1], s[2], s[3]}, (v4f*)p);
        __builtin_nontemporal_store((v4f){s[4], s[5], s[6], s[7]}, (v4f*)(p + 4));
    }
}

extern "C" void kernel_launch(void* const* d_in, const int* in_sizes, int n_in,
                              void* d_out, int out_size, void* d_ws, size_t ws_size,
                              hipStream_t stream) {
    const float* in = (const float*)d_in[0];
    float* out = (float*)d_out;

    const int grid = B * (L / LT) * (C / CT);   // 64*16*2 = 2048
    hipLaunchKernelGGL(lif_repeat_kernel, dim3(grid), dim3(256), 0, stream, in, out);
}

// Round 4
// 54.027 us; speedup vs baseline: 2.2491x; 2.2491x over previous
//
#include <hip/hip_runtime.h>

// LIF "RepeatEncoder": input (B,L,C) f32, output spikes (T,B,C,L) f32.
// v=0; per t: v = v + (a - v)*0.5; s = (v >= 1); v = s ? 0 : v; out[t,b,c,l] = s.
// Input is time-constant, so each thread runs the 16-step recurrence privately.
//
// Round-4: 64l x 32c tile -> 2048 blocks = 8 blocks/CU = 32 waves/CU exactly
// (single wave-round). Each thread owns TWO 4-l chunks (l and l+32) so every
// store instruction's 8 lanes write a dense 128B run per c-row (round-3's
// interleaved mapping half-filled 64B segments -> 2x regression).

#define T_STEPS 16
#define B 64
#define L 512
#define C 128
#define LT 64   // l-tile
#define CT 32   // c-tile

typedef float v4f __attribute__((ext_vector_type(4)));

__global__ __launch_bounds__(256, 8) void lif_repeat_kernel(const float* __restrict__ in,
                                                            float* __restrict__ out) {
    __shared__ float lds[LT][CT + 1];   // +1 pad: transposed reads conflict-free

    const int blk = blockIdx.x;                 // 2048 blocks
    const int c0 = (blk & 3) * CT;              // 4 c-tiles
    const int l0 = ((blk >> 2) & 7) * LT;       // 8 l-tiles
    const int b  = blk >> 5;                    // 64 b
    const int tid = threadIdx.x;

    // Cooperative coalesced load of the 64x32 tile: in[b, l0+r, c0+cc].
    // Each row segment is 128B contiguous.
    const float* inb = in + ((size_t)(b * L + l0)) * C + c0;
#pragma unroll
    for (int k = 0; k < 8; ++k) {
        const int e  = tid + 256 * k;   // 0..2047
        const int r  = e >> 5;          // l-row 0..63
        const int cc = e & 31;          // c    0..31
        lds[r][cc] = inb[(size_t)r * C + cc];
    }
    __syncthreads();

    // Compute mapping: 8 lanes sweep lgrp fastest -> dense 128B stores per c.
    const int lgrp = tid & 7;       // 8 groups of 4 l
    const int c    = tid >> 3;      // 0..31
    const int l    = lgrp * 4;

    float a[8], v[8];
#pragma unroll
    for (int k = 0; k < 4; ++k) {
        a[k]     = lds[l + k][c];        // chunk 0: l .. l+3
        a[4 + k] = lds[32 + l + k][c];   // chunk 1: l+32 .. l+35
        v[k] = 0.f;
        v[4 + k] = 0.f;
    }

    float* outp = out + ((size_t)(b * C + c0 + c)) * L + l0 + l;
    const size_t plane = (size_t)B * C * L;

#pragma unroll
    for (int t = 0; t < T_STEPS; ++t) {
        float s[8];
#pragma unroll
        for (int k = 0; k < 8; ++k) {
            // Exact replication of reference arithmetic: v = v + (x - v)/2.
            // (x-v)*0.5 is exact, so FMA contraction cannot change bits.
            v[k] = v[k] + (a[k] - v[k]) * 0.5f;
            s[k] = (v[k] >= 1.0f) ? 1.0f : 0.0f;
            v[k] = (s[k] != 0.0f) ? 0.0f : v[k];
        }
        float* p = outp + (size_t)t * plane;
        __builtin_nontemporal_store((v4f){s[0], s[1], s[2], s[3]}, (v4f*)p);
        __builtin_nontemporal_store((v4f){s[4], s[5], s[6], s[7]}, (v4f*)(p + 32));
    }
}

extern "C" void kernel_launch(void* const* d_in, const int* in_sizes, int n_in,
                              void* d_out, int out_size, void* d_ws, size_t ws_size,
                              hipStream_t stream) {
    const float* in = (const float*)d_in[0];
    float* out = (float*)d_out;

    const int grid = B * (L / LT) * (C / CT);   // 64*8*4 = 2048
    hipLaunchKernelGGL(lif_repeat_kernel, dim3(grid), dim3(256), 0, stream, in, out);
}

// Round 5
// 48.515 us; speedup vs baseline: 2.5046x; 1.1136x over previous
//
#include <hip/hip_runtime.h>

// LIF "RepeatEncoder": input (B,L,C) f32, output spikes (T,B,C,L) f32.
// v=0; per t: v = v + (a - v)*0.5; s = (v >= 1); v = s ? 0 : v; out[t,b,c,l] = s.
// Input is time-constant, so each thread runs the 16-step recurrence privately.
//
// Round-5: A/B test — identical to round 4 except plain (cached) float4 stores
// instead of nontemporal. Memset hits 6.9 TB/s on this buffer with cached
// stores at 10.5% occupancy; our nt stores sustain only 5.3 TB/s. Isolating
// the nt flag, which was introduced bundled with the LDS transpose in round 2.

#define T_STEPS 16
#define B 64
#define L 512
#define C 128
#define LT 64   // l-tile
#define CT 32   // c-tile

typedef float v4f __attribute__((ext_vector_type(4)));

__global__ __launch_bounds__(256, 8) void lif_repeat_kernel(const float* __restrict__ in,
                                                            float* __restrict__ out) {
    __shared__ float lds[LT][CT + 1];   // +1 pad: transposed reads conflict-free

    const int blk = blockIdx.x;                 // 2048 blocks
    const int c0 = (blk & 3) * CT;              // 4 c-tiles
    const int l0 = ((blk >> 2) & 7) * LT;       // 8 l-tiles
    const int b  = blk >> 5;                    // 64 b
    const int tid = threadIdx.x;

    // Cooperative coalesced load of the 64x32 tile: in[b, l0+r, c0+cc].
    const float* inb = in + ((size_t)(b * L + l0)) * C + c0;
#pragma unroll
    for (int k = 0; k < 8; ++k) {
        const int e  = tid + 256 * k;   // 0..2047
        const int r  = e >> 5;          // l-row 0..63
        const int cc = e & 31;          // c    0..31
        lds[r][cc] = inb[(size_t)r * C + cc];
    }
    __syncthreads();

    // Compute mapping: 8 lanes sweep lgrp fastest -> dense 128B stores per c.
    const int lgrp = tid & 7;       // 8 groups of 4 l
    const int c    = tid >> 3;      // 0..31
    const int l    = lgrp * 4;

    float a[8], v[8];
#pragma unroll
    for (int k = 0; k < 4; ++k) {
        a[k]     = lds[l + k][c];        // chunk 0: l .. l+3
        a[4 + k] = lds[32 + l + k][c];   // chunk 1: l+32 .. l+35
        v[k] = 0.f;
        v[4 + k] = 0.f;
    }

    float* outp = out + ((size_t)(b * C + c0 + c)) * L + l0 + l;
    const size_t plane = (size_t)B * C * L;

#pragma unroll
    for (int t = 0; t < T_STEPS; ++t) {
        float s[8];
#pragma unroll
        for (int k = 0; k < 8; ++k) {
            // Exact replication of reference arithmetic: v = v + (x - v)/2.
            // (x-v)*0.5 is exact, so FMA contraction cannot change bits.
            v[k] = v[k] + (a[k] - v[k]) * 0.5f;
            s[k] = (v[k] >= 1.0f) ? 1.0f : 0.0f;
            v[k] = (s[k] != 0.0f) ? 0.0f : v[k];
        }
        float* p = outp + (size_t)t * plane;
        *reinterpret_cast<v4f*>(p)      = (v4f){s[0], s[1], s[2], s[3]};
        *reinterpret_cast<v4f*>(p + 32) = (v4f){s[4], s[5], s[6], s[7]};
    }
}

extern "C" void kernel_launch(void* const* d_in, const int* in_sizes, int n_in,
                              void* d_out, int out_size, void* d_ws, size_t ws_size,
                              hipStream_t stream) {
    const float* in = (const float*)d_in[0];
    float* out = (float*)d_out;

    const int grid = B * (L / LT) * (C / CT);   // 64*8*4 = 2048
    hipLaunchKernelGGL(lif_repeat_kernel, dim3(grid), dim3(256), 0, stream, in, out);
}